// Round 1
// baseline (2595.332 us; speedup 1.0000x reference)
//
#include <hip/hip_runtime.h>
#include <math.h>

#define F1 64   // input/hidden features
#define F2 40   // classes

// ---------- degree / norm ----------
__global__ void k_init_deg(float* deg, int n) {
    int i = blockIdx.x * blockDim.x + threadIdx.x;
    if (i < n) deg[i] = 1.0f;   // self-loop contributes 1
}

__global__ void k_count(const int* __restrict__ dst, float* deg, int e) {
    int i = blockIdx.x * blockDim.x + threadIdx.x;
    if (i < e) atomicAdd(&deg[dst[i]], 1.0f);
}

__global__ void k_rsqrt(float* d, int n) {
    int i = blockIdx.x * blockDim.x + threadIdx.x;
    if (i < n) d[i] = rsqrtf(d[i]);   // deg >= 1 always
}

__global__ void k_norm(const int* __restrict__ src, const int* __restrict__ dst,
                       const float* __restrict__ dinv, float* __restrict__ norm, int e) {
    int i = blockIdx.x * blockDim.x + threadIdx.x;
    if (i < e) norm[i] = dinv[src[i]] * dinv[dst[i]];
}

// ---------- GEMM1: h = x @ W1   (N x 64) @ (64 x 64) ----------
__global__ __launch_bounds__(256) void k_gemm1(const float* __restrict__ x,
                                               const float* __restrict__ W,
                                               float* __restrict__ h, int n) {
    __shared__ float Ws[64 * 64];
    __shared__ float xs[4][64];
    int tid = threadIdx.x;
#pragma unroll
    for (int i = 0; i < 16; ++i) Ws[tid + i * 256] = W[tid + i * 256];
    int r = tid >> 6, c = tid & 63;
    int row = blockIdx.x * 4 + r;
    xs[r][c] = (row < n) ? x[row * 64 + c] : 0.0f;
    __syncthreads();
    float acc = 0.0f;
#pragma unroll
    for (int k = 0; k < 64; k += 4) {
        float4 xv = *(const float4*)&xs[r][k];
        acc = fmaf(xv.x, Ws[(k + 0) * 64 + c], acc);
        acc = fmaf(xv.y, Ws[(k + 1) * 64 + c], acc);
        acc = fmaf(xv.z, Ws[(k + 2) * 64 + c], acc);
        acc = fmaf(xv.w, Ws[(k + 3) * 64 + c], acc);
    }
    if (row < n) h[row * 64 + c] = acc;
}

// ---------- GEMM2: h2 = relu(agg1) @ W2   (N x 64) @ (64 x 40) ----------
__global__ __launch_bounds__(256) void k_gemm2(const float* __restrict__ a,
                                               const float* __restrict__ W,
                                               float* __restrict__ h, int n) {
    __shared__ float Ws[64 * 40];
    int tid = threadIdx.x;
    for (int i = tid; i < 64 * 40; i += 256) Ws[i] = W[i];
    __syncthreads();
    long long idx = (long long)blockIdx.x * 256 + tid;
    if (idx < (long long)n * 40) {
        int row = (int)(idx / 40);
        int c   = (int)(idx - (long long)row * 40);
        const float* ar = a + (long long)row * 64;
        float acc = 0.0f;
#pragma unroll
        for (int k = 0; k < 64; ++k)
            acc = fmaf(fmaxf(ar[k], 0.0f), Ws[k * 40 + c], acc);
        h[idx] = acc;
    }
}

// ---------- self-loop + bias init ----------
__global__ void k_self1(const float* __restrict__ h, const float* __restrict__ dinv,
                        const float* __restrict__ b, float* __restrict__ agg, int n) {
    int t = blockIdx.x * blockDim.x + threadIdx.x;
    if (t < n * 64) {
        int i = t >> 6, c = t & 63;
        float di = dinv[i];
        agg[t] = b[c] + h[t] * di * di;
    }
}

__global__ void k_self2(const float* __restrict__ h, const float* __restrict__ dinv,
                        const float* __restrict__ b, float* __restrict__ out, int n) {
    int t = blockIdx.x * blockDim.x + threadIdx.x;
    if (t < n * 40) {
        int i = t / 40, c = t - i * 40;
        float di = dinv[i];
        out[t] = b[c] + h[t] * di * di;
    }
}

// ---------- edge scatter, layer 1 (64 feats, 16 threads/edge x float4) ----------
__global__ __launch_bounds__(256) void k_scat1(const int* __restrict__ src,
                                               const int* __restrict__ dst,
                                               const float* __restrict__ norm,
                                               const float* __restrict__ h,
                                               float* agg, int e) {
    long long t = (long long)blockIdx.x * 256 + threadIdx.x;
    int id = (int)(t >> 4);
    int p  = (int)(t & 15);
    if (id < e) {
        int s = src[id], d = dst[id];
        float nm = norm[id];
        float4 v = *(const float4*)&h[s * 64 + p * 4];
        float* ap = agg + d * 64 + p * 4;
        atomicAdd(ap + 0, v.x * nm);
        atomicAdd(ap + 1, v.y * nm);
        atomicAdd(ap + 2, v.z * nm);
        atomicAdd(ap + 3, v.w * nm);
    }
}

// ---------- edge scatter, layer 2 (40 feats, 10 threads/edge x float4) ----------
__global__ __launch_bounds__(256) void k_scat2(const int* __restrict__ src,
                                               const int* __restrict__ dst,
                                               const float* __restrict__ norm,
                                               const float* __restrict__ h,
                                               float* out, int e) {
    long long t = (long long)blockIdx.x * 256 + threadIdx.x;
    int id = (int)(t / 10);
    int p  = (int)(t - (long long)id * 10);
    if (id < e) {
        int s = src[id], d = dst[id];
        float nm = norm[id];
        float4 v = *(const float4*)&h[s * 40 + p * 4];
        float* op = out + d * 40 + p * 4;
        atomicAdd(op + 0, v.x * nm);
        atomicAdd(op + 1, v.y * nm);
        atomicAdd(op + 2, v.z * nm);
        atomicAdd(op + 3, v.w * nm);
    }
}

// ---------- in-place log_softmax over rows of 40 ----------
__global__ __launch_bounds__(256) void k_lsm(float* out, int n) {
    int wave = (int)(((long long)blockIdx.x * 256 + threadIdx.x) >> 6);
    int lane = threadIdx.x & 63;
    if (wave >= n) return;
    float v = (lane < 40) ? out[wave * 40 + lane] : -INFINITY;
    float m = v;
    for (int o = 32; o; o >>= 1) m = fmaxf(m, __shfl_xor(m, o));
    float ex = (lane < 40) ? expf(v - m) : 0.0f;
    float s = ex;
    for (int o = 32; o; o >>= 1) s += __shfl_xor(s, o);
    float ls = logf(s);
    if (lane < 40) out[wave * 40 + lane] = v - m - ls;
}

extern "C" void kernel_launch(void* const* d_in, const int* in_sizes, int n_in,
                              void* d_out, int out_size, void* d_ws, size_t ws_size,
                              hipStream_t stream) {
    const float* x  = (const float*)d_in[0];
    const int*   ei = (const int*)d_in[1];
    const float* W1 = (const float*)d_in[2];
    const float* b1 = (const float*)d_in[3];
    const float* W2 = (const float*)d_in[4];
    const float* b2 = (const float*)d_in[5];

    const int N = in_sizes[0] / F1;      // 100000
    const int E = in_sizes[1] / 2;       // 1600000
    const int* src = ei;
    const int* dst = ei + E;

    float* dinv = (float*)d_ws;              // N
    float* norm = dinv + N;                  // E
    float* bufA = norm + E;                  // N*64  (h1, later h2)
    float* bufB = bufA + (size_t)N * F1;     // N*64  (agg1)
    float* outp = (float*)d_out;             // N*40

    const int B = 256;
    // degree -> dinv -> norm
    k_init_deg<<<(N + B - 1) / B, B, 0, stream>>>(dinv, N);
    k_count<<<(E + B - 1) / B, B, 0, stream>>>(dst, dinv, E);
    k_rsqrt<<<(N + B - 1) / B, B, 0, stream>>>(dinv, N);
    k_norm<<<(E + B - 1) / B, B, 0, stream>>>(src, dst, dinv, norm, E);

    // layer 1
    k_gemm1<<<(N + 3) / 4, B, 0, stream>>>(x, W1, bufA, N);
    k_self1<<<((long long)N * 64 + B - 1) / B, B, 0, stream>>>(bufA, dinv, b1, bufB, N);
    k_scat1<<<((long long)E * 16 + B - 1) / B, B, 0, stream>>>(src, dst, norm, bufA, bufB, E);

    // layer 2 (relu fused into gemm2 read)
    k_gemm2<<<((long long)N * 40 + B - 1) / B, B, 0, stream>>>(bufB, W2, bufA, N);
    k_self2<<<((long long)N * 40 + B - 1) / B, B, 0, stream>>>(bufA, dinv, b2, outp, N);
    k_scat2<<<((long long)E * 10 + B - 1) / B, B, 0, stream>>>(src, dst, norm, bufA, outp, E);

    // log_softmax in place
    k_lsm<<<((long long)N * 64 + B - 1) / B, B, 0, stream>>>(outp, N);
}

// Round 2
// 770.318 us; speedup vs baseline: 3.3692x; 3.3692x over previous
//
#include <hip/hip_runtime.h>
#include <math.h>

#define F1 64   // input/hidden features
#define F2 40   // classes

// ---------- utility ----------
__global__ void k_zero_int(int* p, int n) {
    int i = blockIdx.x * blockDim.x + threadIdx.x;
    if (i < n) p[i] = 0;
}

__global__ void k_count_int(const int* __restrict__ dst, int* deg, int e) {
    int i = blockIdx.x * blockDim.x + threadIdx.x;
    if (i < e) atomicAdd(&deg[dst[i]], 1);
}

__global__ void k_dinv(const int* __restrict__ deg, float* __restrict__ dinv, int n) {
    int i = blockIdx.x * blockDim.x + threadIdx.x;
    if (i < n) dinv[i] = rsqrtf((float)(deg[i] + 1));   // +1 = self loop
}

// ---------- single-workgroup two-level exclusive scan (N <= 1024*chunk) ----------
__global__ __launch_bounds__(1024) void k_scan(const int* __restrict__ deg,
                                               int* __restrict__ row_ptr, int n) {
    __shared__ int sh[1024];
    int t = threadIdx.x;
    int chunk = (n + 1023) >> 10;
    int beg = t * chunk;
    int end = min(beg + chunk, n);
    int s = 0;
    for (int i = beg; i < end; ++i) s += deg[i];
    sh[t] = s;
    __syncthreads();
    // Hillis-Steele inclusive scan over 1024 partials
    for (int off = 1; off < 1024; off <<= 1) {
        int v = (t >= off) ? sh[t - off] : 0;
        __syncthreads();
        sh[t] += v;
        __syncthreads();
    }
    int run = (t == 0) ? 0 : sh[t - 1];
    for (int i = beg; i < end; ++i) { row_ptr[i] = run; run += deg[i]; }
    if (t == 1023) row_ptr[n] = sh[1023];
}

// ---------- bucket edges by dst ----------
__global__ void k_permute(const int* __restrict__ src, const int* __restrict__ dst,
                          const int* __restrict__ row_ptr, int* cnt,
                          int* __restrict__ srcs, int e) {
    int i = blockIdx.x * blockDim.x + threadIdx.x;
    if (i < e) {
        int d = dst[i];
        int pos = row_ptr[d] + atomicAdd(&cnt[d], 1);
        srcs[pos] = src[i];
    }
}

// ---------- GEMM1: h = x @ W1   (N x 64) @ (64 x 64) ----------
__global__ __launch_bounds__(256) void k_gemm1(const float* __restrict__ x,
                                               const float* __restrict__ W,
                                               float* __restrict__ h, int n) {
    __shared__ float Ws[64 * 64];
    __shared__ float xs[4][64];
    int tid = threadIdx.x;
#pragma unroll
    for (int i = 0; i < 16; ++i) Ws[tid + i * 256] = W[tid + i * 256];
    int r = tid >> 6, c = tid & 63;
    int row = blockIdx.x * 4 + r;
    xs[r][c] = (row < n) ? x[row * 64 + c] : 0.0f;
    __syncthreads();
    float acc = 0.0f;
#pragma unroll
    for (int k = 0; k < 64; k += 4) {
        float4 xv = *(const float4*)&xs[r][k];
        acc = fmaf(xv.x, Ws[(k + 0) * 64 + c], acc);
        acc = fmaf(xv.y, Ws[(k + 1) * 64 + c], acc);
        acc = fmaf(xv.z, Ws[(k + 2) * 64 + c], acc);
        acc = fmaf(xv.w, Ws[(k + 3) * 64 + c], acc);
    }
    if (row < n) h[row * 64 + c] = acc;
}

// ---------- CSR gather-aggregate: one wave per node, lane = feature ----------
// out[i,:] = (RELU? relu : id)(h[i,:]) * dinv[i]^2  [+ b]
//          + sum_{e in in(i)} (RELU? relu : id)(h[src,:]) * dinv[src]*dinv[i]
template <bool RELU, bool BIAS>
__global__ __launch_bounds__(256) void k_gather(const float* __restrict__ h,
                                                const int* __restrict__ srcs,
                                                const int* __restrict__ row_ptr,
                                                const float* __restrict__ dinv,
                                                const float* __restrict__ b,
                                                float* __restrict__ out, int n) {
    int node = (int)(((long long)blockIdx.x * 256 + threadIdx.x) >> 6);
    int lane = threadIdx.x & 63;
    if (node >= n) return;
    float di = dinv[node];
    float self = h[(long long)node * 64 + lane];
    if (RELU) self = fmaxf(self, 0.0f);
    float acc = self * di * di;
    if (BIAS) acc += b[lane];
    int e = row_ptr[node], end = row_ptr[node + 1];
    // unroll-by-2 for a little more MLP
    for (; e + 1 < end; e += 2) {
        int s0 = srcs[e], s1 = srcs[e + 1];
        float nm0 = dinv[s0] * di, nm1 = dinv[s1] * di;
        float v0 = h[(long long)s0 * 64 + lane];
        float v1 = h[(long long)s1 * 64 + lane];
        if (RELU) { v0 = fmaxf(v0, 0.0f); v1 = fmaxf(v1, 0.0f); }
        acc = fmaf(v0, nm0, acc);
        acc = fmaf(v1, nm1, acc);
    }
    if (e < end) {
        int s0 = srcs[e];
        float v0 = h[(long long)s0 * 64 + lane];
        if (RELU) v0 = fmaxf(v0, 0.0f);
        acc = fmaf(v0, dinv[s0] * di, acc);
    }
    out[(long long)node * 64 + lane] = acc;
}

// ---------- fused GEMM2 (64->40) + bias + log_softmax, one wave per node ----------
__global__ __launch_bounds__(256) void k_out(const float* __restrict__ agg,
                                             const float* __restrict__ W2,
                                             const float* __restrict__ b2,
                                             float* __restrict__ out, int n) {
    __shared__ float Ws[64 * 40 + 64];   // padded so lane>=40 reads stay in bounds
    int tid = threadIdx.x;
    for (int i = tid; i < 64 * 40; i += 256) Ws[i] = W2[i];
    __syncthreads();
    int node = (int)(((long long)blockIdx.x * 256 + tid) >> 6);
    int lane = tid & 63;
    if (node >= n) return;
    float rv = agg[(long long)node * 64 + lane];   // lane holds element k=lane of the row
    float acc = (lane < 40) ? b2[lane] : 0.0f;
#pragma unroll
    for (int k = 0; k < 64; ++k)
        acc = fmaf(__shfl(rv, k), Ws[k * 40 + lane], acc);
    float v = (lane < 40) ? acc : -INFINITY;
    float m = v;
    for (int o = 32; o; o >>= 1) m = fmaxf(m, __shfl_xor(m, o));
    float ex = (lane < 40) ? expf(v - m) : 0.0f;
    float s = ex;
    for (int o = 32; o; o >>= 1) s += __shfl_xor(s, o);
    float ls = logf(s);
    if (lane < 40) out[(long long)node * 40 + lane] = v - m - ls;
}

extern "C" void kernel_launch(void* const* d_in, const int* in_sizes, int n_in,
                              void* d_out, int out_size, void* d_ws, size_t ws_size,
                              hipStream_t stream) {
    const float* x  = (const float*)d_in[0];
    const int*   ei = (const int*)d_in[1];
    const float* W1 = (const float*)d_in[2];
    const float* b1 = (const float*)d_in[3];
    const float* W2 = (const float*)d_in[4];
    const float* b2 = (const float*)d_in[5];

    const int N = in_sizes[0] / F1;      // 100000
    const int E = in_sizes[1] / 2;       // 1600000
    const int* src = ei;
    const int* dst = ei + E;

    // workspace layout
    int*   ideg    = (int*)d_ws;                       // N   (later reused as cnt)
    int*   row_ptr = ideg + N;                         // N+1
    float* dinv    = (float*)(row_ptr + N + 1);        // N
    int*   srcs    = (int*)(dinv + N);                 // E
    float* bufA    = (float*)(srcs + E);               // N*64
    float* bufB    = bufA + (size_t)N * F1;            // N*64
    float* outp    = (float*)d_out;                    // N*40

    const int B = 256;
    // --- CSR build ---
    k_zero_int<<<(N + B - 1) / B, B, 0, stream>>>(ideg, N);
    k_count_int<<<(E + B - 1) / B, B, 0, stream>>>(dst, ideg, E);
    k_dinv<<<(N + B - 1) / B, B, 0, stream>>>(ideg, dinv, N);
    k_scan<<<1, 1024, 0, stream>>>(ideg, row_ptr, N);
    k_zero_int<<<(N + B - 1) / B, B, 0, stream>>>(ideg, N);   // reuse as cnt
    k_permute<<<(E + B - 1) / B, B, 0, stream>>>(src, dst, row_ptr, ideg, srcs, E);

    // --- layer 1: GEMM then gather-aggregate (+b1) ---
    k_gemm1<<<(N + 3) / 4, B, 0, stream>>>(x, W1, bufA, N);
    k_gather<false, true><<<(N + 3) / 4, B, 0, stream>>>(bufA, srcs, row_ptr, dinv, b1, bufB, N);

    // --- layer 2: aggregate relu(z1) in 64-dim, then fused GEMM2+bias+log_softmax ---
    k_gather<true, false><<<(N + 3) / 4, B, 0, stream>>>(bufB, srcs, row_ptr, dinv, nullptr, bufA, N);
    k_out<<<(N + 3) / 4, B, 0, stream>>>(bufA, W2, b2, outp, N);
}

// Round 3
// 588.500 us; speedup vs baseline: 4.4101x; 1.3090x over previous
//
#include <hip/hip_runtime.h>
#include <math.h>

#define F1 64   // input/hidden features
#define F2 40   // classes

#define SCAN_B 256
#define SCAN_CHUNK 4
#define SCAN_TILE (SCAN_B * SCAN_CHUNK)   // 1024 elems per block

// ---------- utility ----------
__global__ void k_zero_int(int* p, int n) {
    int i = blockIdx.x * blockDim.x + threadIdx.x;
    if (i < n) p[i] = 0;
}

__global__ void k_count_int(const int* __restrict__ dst, int* deg, int e) {
    int i = blockIdx.x * blockDim.x + threadIdx.x;
    if (i < e) atomicAdd(&deg[dst[i]], 1);
}

__global__ void k_dinv(const int* __restrict__ deg, float* __restrict__ dinv, int n) {
    int i = blockIdx.x * blockDim.x + threadIdx.x;
    if (i < n) dinv[i] = rsqrtf((float)(deg[i] + 1));   // +1 = self loop
}

// ---------- multi-block exclusive scan, 3 phases ----------
__global__ __launch_bounds__(SCAN_B) void k_blocksum(const int* __restrict__ deg,
                                                     int* __restrict__ partial, int n) {
    int base = blockIdx.x * SCAN_TILE + threadIdx.x * SCAN_CHUNK;
    int s = 0;
#pragma unroll
    for (int j = 0; j < SCAN_CHUNK; ++j) { int i = base + j; if (i < n) s += deg[i]; }
    for (int o = 32; o; o >>= 1) s += __shfl_down(s, o);
    __shared__ int sh[4];
    if ((threadIdx.x & 63) == 0) sh[threadIdx.x >> 6] = s;
    __syncthreads();
    if (threadIdx.x == 0) partial[blockIdx.x] = sh[0] + sh[1] + sh[2] + sh[3];
}

__global__ __launch_bounds__(256) void k_scan_partial(int* partial, int g) {
    __shared__ int sh[256];
    int t = threadIdx.x;
    int v = (t < g) ? partial[t] : 0;
    sh[t] = v;
    __syncthreads();
    for (int off = 1; off < 256; off <<= 1) {
        int u = (t >= off) ? sh[t - off] : 0;
        __syncthreads();
        sh[t] += u;
        __syncthreads();
    }
    if (t < g) partial[t] = (t == 0) ? 0 : sh[t - 1];
}

__global__ __launch_bounds__(SCAN_B) void k_scan_out(const int* __restrict__ deg,
                                                     const int* __restrict__ partial,
                                                     int* __restrict__ row_ptr, int n) {
    int t = threadIdx.x;
    int base = blockIdx.x * SCAN_TILE + t * SCAN_CHUNK;
    int v[SCAN_CHUNK];
    int s = 0;
#pragma unroll
    for (int j = 0; j < SCAN_CHUNK; ++j) { int i = base + j; v[j] = (i < n) ? deg[i] : 0; s += v[j]; }
    int lane = t & 63;
    int sc = s;
    for (int o = 1; o < 64; o <<= 1) { int u = __shfl_up(sc, o); if (lane >= o) sc += u; }
    __shared__ int wsum[4];
    if (lane == 63) wsum[t >> 6] = sc;
    __syncthreads();
    int w = t >> 6, woff = 0;
#pragma unroll
    for (int k = 0; k < 4; ++k) if (k < w) woff += wsum[k];
    int excl = partial[blockIdx.x] + woff + (sc - s);
#pragma unroll
    for (int j = 0; j < SCAN_CHUNK; ++j) {
        int i = base + j;
        if (i < n) { row_ptr[i] = excl; excl += v[j]; }
    }
    if (base <= n - 1 && n - 1 < base + SCAN_CHUNK) row_ptr[n] = excl;  // total = E
}

// ---------- bucket edges by dst ----------
__global__ void k_permute(const int* __restrict__ src, const int* __restrict__ dst,
                          const int* __restrict__ row_ptr, int* cnt,
                          int* __restrict__ srcs, int e) {
    int i = blockIdx.x * blockDim.x + threadIdx.x;
    if (i < e) {
        int d = dst[i];
        int pos = row_ptr[d] + atomicAdd(&cnt[d], 1);
        srcs[pos] = src[i];
    }
}

// ---------- GEMM1: h = x @ W1   (N x 64) @ (64 x 64) ----------
__global__ __launch_bounds__(256) void k_gemm1(const float* __restrict__ x,
                                               const float* __restrict__ W,
                                               float* __restrict__ h, int n) {
    __shared__ float Ws[64 * 64];
    __shared__ float xs[4][64];
    int tid = threadIdx.x;
#pragma unroll
    for (int i = 0; i < 16; ++i) Ws[tid + i * 256] = W[tid + i * 256];
    int r = tid >> 6, c = tid & 63;
    int row = blockIdx.x * 4 + r;
    xs[r][c] = (row < n) ? x[row * 64 + c] : 0.0f;
    __syncthreads();
    float acc = 0.0f;
#pragma unroll
    for (int k = 0; k < 64; k += 4) {
        float4 xv = *(const float4*)&xs[r][k];
        acc = fmaf(xv.x, Ws[(k + 0) * 64 + c], acc);
        acc = fmaf(xv.y, Ws[(k + 1) * 64 + c], acc);
        acc = fmaf(xv.z, Ws[(k + 2) * 64 + c], acc);
        acc = fmaf(xv.w, Ws[(k + 3) * 64 + c], acc);
    }
    if (row < n) h[row * 64 + c] = acc;
}

// ---------- CSR gather-aggregate: one wave per node, lane = feature ----------
template <bool RELU, bool BIAS>
__global__ __launch_bounds__(256) void k_gather(const float* __restrict__ h,
                                                const int* __restrict__ srcs,
                                                const int* __restrict__ row_ptr,
                                                const float* __restrict__ dinv,
                                                const float* __restrict__ b,
                                                float* __restrict__ out, int n) {
    int node = (int)(((long long)blockIdx.x * 256 + threadIdx.x) >> 6);
    int lane = threadIdx.x & 63;
    if (node >= n) return;
    float di = dinv[node];
    float self = h[(long long)node * 64 + lane];
    if (RELU) self = fmaxf(self, 0.0f);
    float acc = self * di * di;
    if (BIAS) acc += b[lane];
    int e = row_ptr[node], end = row_ptr[node + 1];
    for (; e + 3 < end; e += 4) {
        int s0 = srcs[e], s1 = srcs[e + 1], s2 = srcs[e + 2], s3 = srcs[e + 3];
        float v0 = h[(long long)s0 * 64 + lane];
        float v1 = h[(long long)s1 * 64 + lane];
        float v2 = h[(long long)s2 * 64 + lane];
        float v3 = h[(long long)s3 * 64 + lane];
        float n0 = dinv[s0] * di, n1 = dinv[s1] * di, n2 = dinv[s2] * di, n3 = dinv[s3] * di;
        if (RELU) {
            v0 = fmaxf(v0, 0.0f); v1 = fmaxf(v1, 0.0f);
            v2 = fmaxf(v2, 0.0f); v3 = fmaxf(v3, 0.0f);
        }
        acc = fmaf(v0, n0, acc);
        acc = fmaf(v1, n1, acc);
        acc = fmaf(v2, n2, acc);
        acc = fmaf(v3, n3, acc);
    }
    for (; e < end; ++e) {
        int s0 = srcs[e];
        float v0 = h[(long long)s0 * 64 + lane];
        if (RELU) v0 = fmaxf(v0, 0.0f);
        acc = fmaf(v0, dinv[s0] * di, acc);
    }
    out[(long long)node * 64 + lane] = acc;
}

// ---------- fused GEMM2 (64->40) + bias + log_softmax, one wave per node ----------
__global__ __launch_bounds__(256) void k_out(const float* __restrict__ agg,
                                             const float* __restrict__ W2,
                                             const float* __restrict__ b2,
                                             float* __restrict__ out, int n) {
    __shared__ float Ws[64 * 40 + 64];
    int tid = threadIdx.x;
    for (int i = tid; i < 64 * 40; i += 256) Ws[i] = W2[i];
    __syncthreads();
    int node = (int)(((long long)blockIdx.x * 256 + tid) >> 6);
    int lane = tid & 63;
    if (node >= n) return;
    float rv = agg[(long long)node * 64 + lane];
    float acc = (lane < 40) ? b2[lane] : 0.0f;
#pragma unroll
    for (int k = 0; k < 64; ++k)
        acc = fmaf(__shfl(rv, k), Ws[k * 40 + lane], acc);
    float v = (lane < 40) ? acc : -INFINITY;
    float m = v;
    for (int o = 32; o; o >>= 1) m = fmaxf(m, __shfl_xor(m, o));
    float ex = (lane < 40) ? expf(v - m) : 0.0f;
    float s = ex;
    for (int o = 32; o; o >>= 1) s += __shfl_xor(s, o);
    float ls = logf(s);
    if (lane < 40) out[(long long)node * 40 + lane] = v - m - ls;
}

extern "C" void kernel_launch(void* const* d_in, const int* in_sizes, int n_in,
                              void* d_out, int out_size, void* d_ws, size_t ws_size,
                              hipStream_t stream) {
    const float* x  = (const float*)d_in[0];
    const int*   ei = (const int*)d_in[1];
    const float* W1 = (const float*)d_in[2];
    const float* b1 = (const float*)d_in[3];
    const float* W2 = (const float*)d_in[4];
    const float* b2 = (const float*)d_in[5];

    const int N = in_sizes[0] / F1;      // 100000
    const int E = in_sizes[1] / 2;       // 1600000
    const int* src = ei;
    const int* dst = ei + E;

    // workspace layout
    int*   ideg    = (int*)d_ws;                       // N   (later reused as cnt)
    int*   row_ptr = ideg + N;                         // N+1
    float* dinv    = (float*)(row_ptr + N + 1);        // N
    int*   partial = (int*)(dinv + N);                 // ~128
    int*   srcs    = partial + 256;                    // E
    float* bufA    = (float*)(srcs + E);               // N*64
    float* bufB    = bufA + (size_t)N * F1;            // N*64
    float* outp    = (float*)d_out;                    // N*40

    const int B = 256;
    const int G = (N + SCAN_TILE - 1) / SCAN_TILE;     // scan blocks (98)

    // --- CSR build ---
    k_zero_int<<<(N + B - 1) / B, B, 0, stream>>>(ideg, N);
    k_count_int<<<(E + B - 1) / B, B, 0, stream>>>(dst, ideg, E);
    k_dinv<<<(N + B - 1) / B, B, 0, stream>>>(ideg, dinv, N);
    k_blocksum<<<G, SCAN_B, 0, stream>>>(ideg, partial, N);
    k_scan_partial<<<1, 256, 0, stream>>>(partial, G);
    k_scan_out<<<G, SCAN_B, 0, stream>>>(ideg, partial, row_ptr, N);
    k_zero_int<<<(N + B - 1) / B, B, 0, stream>>>(ideg, N);   // reuse as cnt
    k_permute<<<(E + B - 1) / B, B, 0, stream>>>(src, dst, row_ptr, ideg, srcs, E);

    // --- layer 1: GEMM then gather-aggregate (+b1) ---
    k_gemm1<<<(N + 3) / 4, B, 0, stream>>>(x, W1, bufA, N);
    k_gather<false, true><<<(N + 3) / 4, B, 0, stream>>>(bufA, srcs, row_ptr, dinv, b1, bufB, N);

    // --- layer 2: aggregate relu(z1), then fused GEMM2+bias+log_softmax ---
    k_gather<true, false><<<(N + 3) / 4, B, 0, stream>>>(bufB, srcs, row_ptr, dinv, nullptr, bufA, N);
    k_out<<<(N + 3) / 4, B, 0, stream>>>(bufA, W2, b2, outp, N);
}

// Round 4
// 517.119 us; speedup vs baseline: 5.0188x; 1.1380x over previous
//
#include <hip/hip_runtime.h>
#include <math.h>

#define F1 64   // input/hidden features
#define F2 40   // classes

#define SCAN_B 256
#define SCAN_CHUNK 4
#define SCAN_TILE (SCAN_B * SCAN_CHUNK)   // 1024 elems per block

// ---------- utility ----------
__global__ void k_zero_int(int* p, int n) {
    int i = blockIdx.x * blockDim.x + threadIdx.x;
    if (i < n) p[i] = 0;
}

__global__ void k_count_int(const int* __restrict__ dst, int* deg, int e) {
    int i = blockIdx.x * blockDim.x + threadIdx.x;
    if (i < e) atomicAdd(&deg[dst[i]], 1);
}

__global__ void k_dinv(const int* __restrict__ deg, float* __restrict__ dinv, int n) {
    int i = blockIdx.x * blockDim.x + threadIdx.x;
    if (i < n) dinv[i] = rsqrtf((float)(deg[i] + 1));   // +1 = self loop
}

// ---------- multi-block exclusive scan, 3 phases ----------
__global__ __launch_bounds__(SCAN_B) void k_blocksum(const int* __restrict__ deg,
                                                     int* __restrict__ partial, int n) {
    int base = blockIdx.x * SCAN_TILE + threadIdx.x * SCAN_CHUNK;
    int s = 0;
#pragma unroll
    for (int j = 0; j < SCAN_CHUNK; ++j) { int i = base + j; if (i < n) s += deg[i]; }
    for (int o = 32; o; o >>= 1) s += __shfl_down(s, o);
    __shared__ int sh[4];
    if ((threadIdx.x & 63) == 0) sh[threadIdx.x >> 6] = s;
    __syncthreads();
    if (threadIdx.x == 0) partial[blockIdx.x] = sh[0] + sh[1] + sh[2] + sh[3];
}

__global__ __launch_bounds__(256) void k_scan_partial(int* partial, int g) {
    __shared__ int sh[256];
    int t = threadIdx.x;
    int v = (t < g) ? partial[t] : 0;
    sh[t] = v;
    __syncthreads();
    for (int off = 1; off < 256; off <<= 1) {
        int u = (t >= off) ? sh[t - off] : 0;
        __syncthreads();
        sh[t] += u;
        __syncthreads();
    }
    if (t < g) partial[t] = (t == 0) ? 0 : sh[t - 1];
}

__global__ __launch_bounds__(SCAN_B) void k_scan_out(const int* __restrict__ deg,
                                                     const int* __restrict__ partial,
                                                     int* __restrict__ row_ptr, int n) {
    int t = threadIdx.x;
    int base = blockIdx.x * SCAN_TILE + t * SCAN_CHUNK;
    int v[SCAN_CHUNK];
    int s = 0;
#pragma unroll
    for (int j = 0; j < SCAN_CHUNK; ++j) { int i = base + j; v[j] = (i < n) ? deg[i] : 0; s += v[j]; }
    int lane = t & 63;
    int sc = s;
    for (int o = 1; o < 64; o <<= 1) { int u = __shfl_up(sc, o); if (lane >= o) sc += u; }
    __shared__ int wsum[4];
    if (lane == 63) wsum[t >> 6] = sc;
    __syncthreads();
    int w = t >> 6, woff = 0;
#pragma unroll
    for (int k = 0; k < 4; ++k) if (k < w) woff += wsum[k];
    int excl = partial[blockIdx.x] + woff + (sc - s);
#pragma unroll
    for (int j = 0; j < SCAN_CHUNK; ++j) {
        int i = base + j;
        if (i < n) { row_ptr[i] = excl; excl += v[j]; }
    }
    if (base <= n - 1 && n - 1 < base + SCAN_CHUNK) row_ptr[n] = excl;  // total = E
}

// ---------- bucket edges by dst ----------
__global__ void k_permute(const int* __restrict__ src, const int* __restrict__ dst,
                          const int* __restrict__ row_ptr, int* cnt,
                          int* __restrict__ srcs, int e) {
    int i = blockIdx.x * blockDim.x + threadIdx.x;
    if (i < e) {
        int d = dst[i];
        int pos = row_ptr[d] + atomicAdd(&cnt[d], 1);
        srcs[pos] = src[i];
    }
}

// ---------- GEMM1: h = x @ W1   (N x 64) @ (64 x 64) ----------
__global__ __launch_bounds__(256) void k_gemm1(const float* __restrict__ x,
                                               const float* __restrict__ W,
                                               float* __restrict__ h, int n) {
    __shared__ float Ws[64 * 64];
    __shared__ float xs[4][64];
    int tid = threadIdx.x;
#pragma unroll
    for (int i = 0; i < 16; ++i) Ws[tid + i * 256] = W[tid + i * 256];
    int r = tid >> 6, c = tid & 63;
    int row = blockIdx.x * 4 + r;
    xs[r][c] = (row < n) ? x[row * 64 + c] : 0.0f;
    __syncthreads();
    float acc = 0.0f;
#pragma unroll
    for (int k = 0; k < 64; k += 4) {
        float4 xv = *(const float4*)&xs[r][k];
        acc = fmaf(xv.x, Ws[(k + 0) * 64 + c], acc);
        acc = fmaf(xv.y, Ws[(k + 1) * 64 + c], acc);
        acc = fmaf(xv.z, Ws[(k + 2) * 64 + c], acc);
        acc = fmaf(xv.w, Ws[(k + 3) * 64 + c], acc);
    }
    if (row < n) h[row * 64 + c] = acc;
}

// ---------- CSR gather-aggregate: one wave per node, lane = feature ----------
template <bool RELU, bool BIAS>
__global__ __launch_bounds__(256) void k_gather(const float* __restrict__ h,
                                                const int* __restrict__ srcs,
                                                const int* __restrict__ row_ptr,
                                                const float* __restrict__ dinv,
                                                const float* __restrict__ b,
                                                float* __restrict__ out, int n) {
    int node = (int)(((long long)blockIdx.x * 256 + threadIdx.x) >> 6);
    int lane = threadIdx.x & 63;
    if (node >= n) return;
    float di = dinv[node];
    float self = h[(long long)node * 64 + lane];
    if (RELU) self = fmaxf(self, 0.0f);
    float acc = self * di * di;
    if (BIAS) acc += b[lane];
    int e = row_ptr[node], end = row_ptr[node + 1];
    for (; e + 3 < end; e += 4) {
        int s0 = srcs[e], s1 = srcs[e + 1], s2 = srcs[e + 2], s3 = srcs[e + 3];
        float v0 = h[(long long)s0 * 64 + lane];
        float v1 = h[(long long)s1 * 64 + lane];
        float v2 = h[(long long)s2 * 64 + lane];
        float v3 = h[(long long)s3 * 64 + lane];
        float n0 = dinv[s0] * di, n1 = dinv[s1] * di, n2 = dinv[s2] * di, n3 = dinv[s3] * di;
        if (RELU) {
            v0 = fmaxf(v0, 0.0f); v1 = fmaxf(v1, 0.0f);
            v2 = fmaxf(v2, 0.0f); v3 = fmaxf(v3, 0.0f);
        }
        acc = fmaf(v0, n0, acc);
        acc = fmaf(v1, n1, acc);
        acc = fmaf(v2, n2, acc);
        acc = fmaf(v3, n3, acc);
    }
    for (; e < end; ++e) {
        int s0 = srcs[e];
        float v0 = h[(long long)s0 * 64 + lane];
        if (RELU) v0 = fmaxf(v0, 0.0f);
        acc = fmaf(v0, dinv[s0] * di, acc);
    }
    out[(long long)node * 64 + lane] = acc;
}

// ---------- fused GEMM2 (64->40) + bias + log_softmax ----------
// lane = class; W2 column lives in 64 VGPRs; agg row read via wave-uniform
// scalar loads (readfirstlane) -> s_load broadcast; no LDS in the loop.
__global__ __launch_bounds__(256) void k_out(const float* __restrict__ agg,
                                             const float* __restrict__ W2,
                                             const float* __restrict__ b2,
                                             float* __restrict__ out, int n,
                                             int nwaves) {
    int wid = blockIdx.x * 4 + (threadIdx.x >> 6);
    int lane = threadIdx.x & 63;
    float wcol[64];
#pragma unroll
    for (int k = 0; k < 64; ++k)
        wcol[k] = (lane < 40) ? W2[k * 40 + lane] : 0.0f;
    float bias = (lane < 40) ? b2[lane] : 0.0f;
    for (int node = wid; node < n; node += nwaves) {
        int node_u = __builtin_amdgcn_readfirstlane(node);
        const float* arow = agg + (size_t)node_u * 64;
        float acc = bias;
#pragma unroll
        for (int k4 = 0; k4 < 16; ++k4) {
            float4 a = *(const float4*)(arow + k4 * 4);   // wave-uniform -> s_load
            acc = fmaf(a.x, wcol[k4 * 4 + 0], acc);
            acc = fmaf(a.y, wcol[k4 * 4 + 1], acc);
            acc = fmaf(a.z, wcol[k4 * 4 + 2], acc);
            acc = fmaf(a.w, wcol[k4 * 4 + 3], acc);
        }
        float v = (lane < 40) ? acc : -INFINITY;
        float m = v;
        for (int o = 32; o; o >>= 1) m = fmaxf(m, __shfl_xor(m, o));
        float ex = (lane < 40) ? expf(v - m) : 0.0f;
        float s = ex;
        for (int o = 32; o; o >>= 1) s += __shfl_xor(s, o);
        float r = v - m - logf(s);
        if (lane < 40) out[(size_t)node_u * 40 + lane] = r;
    }
}

extern "C" void kernel_launch(void* const* d_in, const int* in_sizes, int n_in,
                              void* d_out, int out_size, void* d_ws, size_t ws_size,
                              hipStream_t stream) {
    const float* x  = (const float*)d_in[0];
    const int*   ei = (const int*)d_in[1];
    const float* W1 = (const float*)d_in[2];
    const float* b1 = (const float*)d_in[3];
    const float* W2 = (const float*)d_in[4];
    const float* b2 = (const float*)d_in[5];

    const int N = in_sizes[0] / F1;      // 100000
    const int E = in_sizes[1] / 2;       // 1600000
    const int* src = ei;
    const int* dst = ei + E;

    // workspace layout
    int*   ideg    = (int*)d_ws;                       // N   (later reused as cnt)
    int*   row_ptr = ideg + N;                         // N+1
    float* dinv    = (float*)(row_ptr + N + 1);        // N
    int*   partial = (int*)(dinv + N);                 // ~128
    int*   srcs    = partial + 256;                    // E
    float* bufA    = (float*)(srcs + E);               // N*64
    float* bufB    = bufA + (size_t)N * F1;            // N*64
    float* outp    = (float*)d_out;                    // N*40

    const int B = 256;
    const int G = (N + SCAN_TILE - 1) / SCAN_TILE;     // scan blocks (98)

    // --- CSR build ---
    k_zero_int<<<(N + B - 1) / B, B, 0, stream>>>(ideg, N);
    k_count_int<<<(E + B - 1) / B, B, 0, stream>>>(dst, ideg, E);
    k_dinv<<<(N + B - 1) / B, B, 0, stream>>>(ideg, dinv, N);
    k_blocksum<<<G, SCAN_B, 0, stream>>>(ideg, partial, N);
    k_scan_partial<<<1, 256, 0, stream>>>(partial, G);
    k_scan_out<<<G, SCAN_B, 0, stream>>>(ideg, partial, row_ptr, N);
    k_zero_int<<<(N + B - 1) / B, B, 0, stream>>>(ideg, N);   // reuse as cnt
    k_permute<<<(E + B - 1) / B, B, 0, stream>>>(src, dst, row_ptr, ideg, srcs, E);

    // --- layer 1: GEMM then gather-aggregate (+b1) ---
    k_gemm1<<<(N + 3) / 4, B, 0, stream>>>(x, W1, bufA, N);
    k_gather<false, true><<<(N + 3) / 4, B, 0, stream>>>(bufA, srcs, row_ptr, dinv, b1, bufB, N);

    // --- layer 2: aggregate relu(z1), then fused GEMM2+bias+log_softmax ---
    k_gather<true, false><<<(N + 3) / 4, B, 0, stream>>>(bufB, srcs, row_ptr, dinv, nullptr, bufA, N);
    const int OUT_BLOCKS = 2048;
    k_out<<<OUT_BLOCKS, B, 0, stream>>>(bufA, W2, b2, outp, N, OUT_BLOCKS * 4);
}